// Round 11
// baseline (30.979 us; speedup 1.0000x reference)
//
#include <hip/hip_runtime.h>
#include <hip/hip_bf16.h>

#define BB 8
#define NN 2048
#define EE 64
#define DD 128
#define BN (BB * NN)

typedef __attribute__((ext_vector_type(8))) short short8v;
typedef __attribute__((ext_vector_type(4))) float float4v;

__device__ __forceinline__ short f2bf(float f) {
    __hip_bfloat16 h = __float2bfloat16(f);
    return *reinterpret_cast<short*>(&h);
}
__device__ __forceinline__ uint32_t pack2bf(float a, float b) {
    return (uint32_t)(uint16_t)f2bf(a) | ((uint32_t)(uint16_t)f2bf(b) << 16);
}

#define GLD16(gp, lp)                                                          \
    __builtin_amdgcn_global_load_lds(                                          \
        (const __attribute__((address_space(1))) void*)(gp),                   \
        (__attribute__((address_space(3))) void*)(lp), 16, 0, 0)
#define GLD4(gp, lp)                                                           \
    __builtin_amdgcn_global_load_lds(                                          \
        (const __attribute__((address_space(1))) void*)(gp),                   \
        (__attribute__((address_space(3))) void*)(lp), 4, 0, 0)

// ---------------- fused prep: embq | zq | sq ----------------
__global__ __launch_bounds__(256) void prep_kernel(const float* __restrict__ emb,
                                                   const float* __restrict__ z,
                                                   short* __restrict__ embq,
                                                   short* __restrict__ zq,
                                                   float* __restrict__ sq) {
    __shared__ float zl[64 * 129];
    const int bid = blockIdx.x;
    const int t = threadIdx.x;

    if (bid < 512) {
        int gid = bid * 256 + t;
        int s = gid & 63;
        int ke = (gid >> 6) & 1;
        int r16 = (gid >> 7) & 127;
        int b = gid >> 14;
        int i = r16 * 16 + (s & 15);
        int e0 = ke * 32 + ((s >> 4) & 3) * 8;
        const float4* src = reinterpret_cast<const float4*>(emb + ((size_t)(b * NN + i)) * EE + e0);
        float4 v0 = src[0], v1 = src[1];
        short8v o;
        o[0] = f2bf(v0.x); o[1] = f2bf(v0.y); o[2] = f2bf(v0.z); o[3] = f2bf(v0.w);
        o[4] = f2bf(v1.x); o[5] = f2bf(v1.y); o[6] = f2bf(v1.z); o[7] = f2bf(v1.w);
        *reinterpret_cast<short8v*>(embq + (size_t)gid * 8) = o;
    } else if (bid < 768) {
        int v = bid - 512;  // b*32 + jt
        int b = v >> 5;
        int jt = v & 31;
        int jb = jt * 64;
#pragma unroll
        for (int k = 0; k < 8; ++k) {
            int idx = t + k * 256;
            int jl = idx >> 5, c4 = idx & 31;
            float4 w = reinterpret_cast<const float4*>(z + ((size_t)(b * NN + jb + jl)) * DD)[c4];
            float* p = &zl[jl * 129 + c4 * 4];
            p[0] = w.x; p[1] = w.y; p[2] = w.z; p[3] = w.w;
        }
        __syncthreads();
#pragma unroll
        for (int k = 0; k < 4; ++k) {
            int sid = t + k * 256;
            int blk = sid >> 6, s = sid & 63;
            int ktl = blk >> 3, nt = blk & 7;
            int d = nt * 16 + (s & 15);
            int jl = ktl * 32 + ((s >> 4) & 3) * 8;
            short8v o;
#pragma unroll
            for (int e = 0; e < 8; ++e) o[e] = f2bf(zl[(jl + e) * 129 + d]);
            *reinterpret_cast<short8v*>(zq + ((size_t)((b * 64 + jt * 2 + ktl) * 8 + nt) * 64 + s) * 8) = o;
        }
    } else {
        int v = bid - 768;
        int q = t & 15;
#pragma unroll
        for (int p = 0; p < 4; ++p) {
            int row = v * 64 + p * 16 + (t >> 4);
            float4 rv = reinterpret_cast<const float4*>(emb + (size_t)row * EE)[q];
            float a0 = __bfloat162float(__float2bfloat16(rv.x));
            float a1 = __bfloat162float(__float2bfloat16(rv.y));
            float a2 = __bfloat162float(__float2bfloat16(rv.z));
            float a3 = __bfloat162float(__float2bfloat16(rv.w));
            float s2 = a0 * a0 + a1 * a1 + a2 * a2 + a3 * a3;
#pragma unroll
            for (int off = 1; off < 16; off <<= 1) s2 += __shfl_xor(s2, off);
            if (q == 0) sq[row] = s2;
        }
    }
}

// ---------------- main MFMA attention: 128-row blocks, 32 rows/wave ----------------
// grid: bid = ((js*16 + it))*8 + b (XCD-pinned batch). 4 waves; wave owns 32 rows (m=0,1).
// QK (swapped): lane (g,c), group m holds S[i=w*32+m*16+c][j=J*16+4g+r]. Each embJ
// afrag ds_read feeds 2 MFMAs (halved LDS redundancy vs 16-row waves).
// Vote-before-exp skips negligible work (p < 1e-6, bounded truncation ~0.011 worst case).
// Counted-vmcnt pipeline: compute(cur); barA; STAGE(cur, jt+2); vmcnt(3); barB.
__global__ __launch_bounds__(256, 2) void attn_mfma(const short* __restrict__ embq,
                                                    const short* __restrict__ zq,
                                                    const float* __restrict__ sq,
                                                    float* __restrict__ outnum,
                                                    float* __restrict__ den,
                                                    int njs) {
    __shared__ short sU[4][2048];      // 16KB union: embI staging (128 rows) -> per-wave P^T (4KB)
    __shared__ int4 sEmbJ[2][512];     // 16KB dbuf [jfr(4)][ke(2)][64]
    __shared__ float sSqJ[2][4][64];   // 2KB dbuf, per-wave copy (uniform 3-op stages)

    const int t = threadIdx.x;
    const int bid = blockIdx.x;
    const int b = bid & 7;
    const int q = bid >> 3;
    const int it = q & 15;
    const int js = q >> 4;
    const int ib = it * 128;
    const int w = t >> 6;
    const int l = t & 63;
    const int g = (l >> 4) & 3;
    const int c = l & 15;

    const int4* embqI4 = (const int4*)embq;
    const short8v* zq8 = (const short8v*)zq;
    const float* sqB = sq + b * NN;

    const int ntiles = 32 / njs;
    const int jt0 = js * ntiles;
    const int jtEnd = jt0 + ntiles;

    int4* sUi = (int4*)&sU[0][0];

    // stage = 3 VMEM ops per thread, uniform across all waves
#define STAGE(buf, tile)                                                       \
    do {                                                                       \
        const int4* _sj = embqI4 + (size_t)(b * 128 + (tile) * 4) * 2 * 64;    \
        GLD16(_sj + t, &sEmbJ[buf][t]);                                        \
        GLD16(_sj + t + 256, &sEmbJ[buf][t + 256]);                            \
        GLD4(sqB + (tile) * 64 + l, &sSqJ[buf][w][0]);                         \
    } while (0)

    // prologue: embI (4 ops, 128 rows) + stage(jt0) + stage(jt0+1); wait embI+tile0
    {
        const int4* srcI = embqI4 + (size_t)(b * 128 + it * 8) * 2 * 64;
#pragma unroll
        for (int k = 0; k < 4; ++k) GLD16(srcI + t + k * 256, sUi + t + k * 256);
    }
    STAGE(0, jt0);
    STAGE(1, jt0 + 1);
    asm volatile("s_waitcnt vmcnt(3)" ::: "memory");  // embI + tile0 done; tile1 in flight
    __builtin_amdgcn_s_barrier();
    __builtin_amdgcn_sched_barrier(0);

    // wave w reads exactly its own sU[w] 4KB region (groups w*2+m), later its P^T scratch
    short8v qkB[2][2];
#pragma unroll
    for (int m = 0; m < 2; ++m)
#pragma unroll
        for (int ke = 0; ke < 2; ++ke)
            qkB[m][ke] = *reinterpret_cast<const short8v*>(&sUi[((w * 2 + m) * 2 + ke) * 64 + l]);
    float sqi[2];
#pragma unroll
    for (int m = 0; m < 2; ++m) sqi[m] = sqB[ib + w * 32 + m * 16 + c];

    float dsum[2] = {0.f, 0.f};
    float4v acc[2][8];
#pragma unroll
    for (int m = 0; m < 2; ++m)
#pragma unroll
        for (int nt = 0; nt < 8; ++nt) acc[m][nt] = (float4v){0.f, 0.f, 0.f, 0.f};

    char* ptw = (char*)&sU[w][0];
    const int swz = (c & 7) << 4;

    int cur = 0;
    for (int jt = jt0; jt < jtEnd; ++jt, cur ^= 1) {
        // ---- QK (swapped) + d2 only; no exp yet ----
        float d2v[2][4][4];
        float d2minJ[4];
#pragma unroll
        for (int J = 0; J < 4; ++J) {
            short8v a0 = *reinterpret_cast<const short8v*>(&sEmbJ[cur][(J * 2 + 0) * 64 + l]);
            short8v a1 = *reinterpret_cast<const short8v*>(&sEmbJ[cur][(J * 2 + 1) * 64 + l]);
            float4 sqj = *reinterpret_cast<const float4*>(&sSqJ[cur][w][J * 16 + 4 * g]);
            float mn = 1e30f;
#pragma unroll
            for (int m = 0; m < 2; ++m) {
                float4v sfr = (float4v){0.f, 0.f, 0.f, 0.f};
                sfr = __builtin_amdgcn_mfma_f32_16x16x32_bf16(a0, qkB[m][0], sfr, 0, 0, 0);
                sfr = __builtin_amdgcn_mfma_f32_16x16x32_bf16(a1, qkB[m][1], sfr, 0, 0, 0);
                d2v[m][J][0] = fmaxf(fmaf(-2.0f, sfr[0], sqi[m] + sqj.x), 0.0f);
                d2v[m][J][1] = fmaxf(fmaf(-2.0f, sfr[1], sqi[m] + sqj.y), 0.0f);
                d2v[m][J][2] = fmaxf(fmaf(-2.0f, sfr[2], sqi[m] + sqj.z), 0.0f);
                d2v[m][J][3] = fmaxf(fmaf(-2.0f, sfr[3], sqi[m] + sqj.w), 0.0f);
                mn = fminf(mn, fminf(fminf(d2v[m][J][0], d2v[m][J][1]),
                                     fminf(d2v[m][J][2], d2v[m][J][3])));
            }
            d2minJ[J] = mn;
        }
        float tmin = fminf(fminf(d2minJ[0], d2minJ[1]), fminf(d2minJ[2], d2minJ[3]));

        // ---- exp/pack/PV only when some p >= 1e-6 anywhere in the wave-tile ----
        if (!__all(tmin > 13.8f)) {
#pragma unroll
            for (int J = 0; J < 4; ++J) {
                const bool live = !__all(d2minJ[J] > 13.8f);
#pragma unroll
                for (int m = 0; m < 2; ++m) {
                    unsigned long long pword = 0ull;
                    if (live) {
                        float p0 = __expf(-d2v[m][J][0]);
                        float p1 = __expf(-d2v[m][J][1]);
                        float p2 = __expf(-d2v[m][J][2]);
                        float p3 = __expf(-d2v[m][J][3]);
                        dsum[m] += (p0 + p1) + (p2 + p3);
                        pword = (unsigned long long)pack2bf(p0, p1) |
                                ((unsigned long long)pack2bf(p2, p3) << 32);
                    }
                    *reinterpret_cast<unsigned long long*>(
                        ptw + ((m * 2048 + c * 128 + g * 8) ^ swz ^ (J * 32))) = pword;
                }
            }
            short8v pa[2][2];
#pragma unroll
            for (int m = 0; m < 2; ++m)
#pragma unroll
                for (int kt = 0; kt < 2; ++kt)
                    pa[m][kt] = *reinterpret_cast<const short8v*>(
                        ptw + ((m * 2048 + c * 128 + kt * 64 + g * 16) ^ swz));
#pragma unroll
            for (int nt = 0; nt < 8; ++nt) {
                short8v z0 = zq8[(size_t)((b * 64 + jt * 2 + 0) * 8 + nt) * 64 + l];
                short8v z1 = zq8[(size_t)((b * 64 + jt * 2 + 1) * 8 + nt) * 64 + l];
#pragma unroll
                for (int m = 0; m < 2; ++m) {
                    acc[m][nt] = __builtin_amdgcn_mfma_f32_16x16x32_bf16(pa[m][0], z0, acc[m][nt], 0, 0, 0);
                    acc[m][nt] = __builtin_amdgcn_mfma_f32_16x16x32_bf16(pa[m][1], z1, acc[m][nt], 0, 0, 0);
                }
            }
        }

        // ---- pipeline boundary (no full drain in steady state) ----
        __builtin_amdgcn_s_barrier();  // (A) all waves done reading buf[cur]
        if (jt + 2 < jtEnd) {
            STAGE(cur, jt + 2);        // overwrite freed buffer; stays in flight
            asm volatile("s_waitcnt vmcnt(3)" ::: "memory");  // retire tile jt+1's stage
        } else {
            asm volatile("s_waitcnt vmcnt(0)" ::: "memory");  // tail: drain remaining
        }
        __builtin_amdgcn_s_barrier();  // (B) next tile visible to all waves
        __builtin_amdgcn_sched_barrier(0);
    }
#undef STAGE

    // dsum reduce over g-groups -> all lanes hold row (m, c) sums
#pragma unroll
    for (int m = 0; m < 2; ++m) {
        dsum[m] += __shfl_xor(dsum[m], 16);
        dsum[m] += __shfl_xor(dsum[m], 32);
    }

    if (njs == 1) {
#pragma unroll
        for (int m = 0; m < 2; ++m) {
            float invr[4];
#pragma unroll
            for (int r = 0; r < 4; ++r) invr[r] = 1.0f / __shfl(dsum[m], 4 * g + r);
#pragma unroll
            for (int r = 0; r < 4; ++r) {
                size_t row = (size_t)(b * NN + ib + w * 32 + m * 16 + 4 * g + r);
#pragma unroll
                for (int nt = 0; nt < 8; ++nt)
                    outnum[row * DD + nt * 16 + c] = acc[m][nt][r] * invr[r];
            }
        }
    } else {
        if (l < 16) {
            den[(size_t)js * BN + b * NN + ib + w * 32 + l] = dsum[0];
            den[(size_t)js * BN + b * NN + ib + w * 32 + 16 + l] = dsum[1];
        }
        // skip num writes when this wave's whole j-slice carries no mass
        if (!__all(fmaxf(dsum[0], dsum[1]) < 1e-6f)) {
#pragma unroll
            for (int m = 0; m < 2; ++m)
#pragma unroll
                for (int r = 0; r < 4; ++r) {
                    size_t row = (size_t)js * BN + b * NN + ib + w * 32 + m * 16 + 4 * g + r;
#pragma unroll
                    for (int nt = 0; nt < 8; ++nt)
                        outnum[row * DD + nt * 16 + c] = acc[m][nt][r];
                }
        }
    }
}

// ---------------- reduce: out = sum_js num / sum_js den, num reads gated by den ----------------
__global__ __launch_bounds__(256) void reduce_kernel(const float4* __restrict__ num,
                                                     const float* __restrict__ den,
                                                     float4* __restrict__ out,
                                                     int njs) {
    int i4 = blockIdx.x * 256 + threadIdx.x;
    int row = i4 >> 5;
    float4 ns = make_float4(0.f, 0.f, 0.f, 0.f);
    float ds = 0.f;
    for (int js = 0; js < njs; ++js) {
        float dj = den[(size_t)js * BN + row];
        ds += dj;
        if (dj >= 1e-6f) {
            float4 v = num[(size_t)js * ((size_t)BN * (DD / 4)) + i4];
            ns.x += v.x; ns.y += v.y; ns.z += v.z; ns.w += v.w;
        }
    }
    float inv = 1.0f / ds;
    out[i4] = make_float4(ns.x * inv, ns.y * inv, ns.z * inv, ns.w * inv);
}

extern "C" void kernel_launch(void* const* d_in, const int* in_sizes, int n_in,
                              void* d_out, int out_size, void* d_ws, size_t ws_size,
                              hipStream_t stream) {
    (void)in_sizes; (void)n_in; (void)out_size;
    const float* emb = (const float*)d_in[0];
    const float* z = (const float*)d_in[1];
    float* out = (float*)d_out;
    float* ws = (float*)d_ws;

    // ws layout (floats): sq[BN] | den[njs*BN] | num[njs*BN*DD] | embq(1M shorts) | zq(2M shorts)
    int njs = 1;
    if (ws_size >= 40ull * 1024 * 1024) njs = 4;
    else if (ws_size >= 24ull * 1024 * 1024) njs = 2;

    float* sqw = ws;
    float* denw = ws + BN;
    float* numw = denw + (size_t)njs * BN;
    size_t numFloats = (njs > 1) ? (size_t)njs * BN * DD : 0;
    short* embqw = (short*)(numw + numFloats);
    short* zqw = embqw + (size_t)BB * NN * EE;

    prep_kernel<<<1024, 256, 0, stream>>>(emb, z, embqw, zqw, sqw);

    attn_mfma<<<8 * 16 * njs, 256, 0, stream>>>(embqw, zqw, sqw,
                                                njs == 1 ? out : numw, denw, njs);

    if (njs > 1) {
        reduce_kernel<<<(BN * (DD / 4)) / 256, 256, 0, stream>>>(
            (const float4*)numw, denw, (float4*)out, njs);
    }
}

// Round 12
// 30.479 us; speedup vs baseline: 1.0164x; 1.0164x over previous
//
#include <hip/hip_runtime.h>
#include <hip/hip_bf16.h>

#define BB 8
#define NN 2048
#define EE 64
#define DD 128
#define BN (BB * NN)

typedef __attribute__((ext_vector_type(8))) short short8v;
typedef __attribute__((ext_vector_type(4))) float float4v;

__device__ __forceinline__ short f2bf(float f) {
    __hip_bfloat16 h = __float2bfloat16(f);
    return *reinterpret_cast<short*>(&h);
}
__device__ __forceinline__ uint32_t pack2bf(float a, float b) {
    return (uint32_t)(uint16_t)f2bf(a) | ((uint32_t)(uint16_t)f2bf(b) << 16);
}

// ---------------- fused prep: embq | zq | sq ----------------
__global__ __launch_bounds__(256) void prep_kernel(const float* __restrict__ emb,
                                                   const float* __restrict__ z,
                                                   short* __restrict__ embq,
                                                   short* __restrict__ zq,
                                                   float* __restrict__ sq) {
    __shared__ float zl[64 * 129];
    const int bid = blockIdx.x;
    const int t = threadIdx.x;

    if (bid < 512) {
        int gid = bid * 256 + t;
        int s = gid & 63;
        int ke = (gid >> 6) & 1;
        int r16 = (gid >> 7) & 127;
        int b = gid >> 14;
        int i = r16 * 16 + (s & 15);
        int e0 = ke * 32 + ((s >> 4) & 3) * 8;
        const float4* src = reinterpret_cast<const float4*>(emb + ((size_t)(b * NN + i)) * EE + e0);
        float4 v0 = src[0], v1 = src[1];
        short8v o;
        o[0] = f2bf(v0.x); o[1] = f2bf(v0.y); o[2] = f2bf(v0.z); o[3] = f2bf(v0.w);
        o[4] = f2bf(v1.x); o[5] = f2bf(v1.y); o[6] = f2bf(v1.z); o[7] = f2bf(v1.w);
        *reinterpret_cast<short8v*>(embq + (size_t)gid * 8) = o;
    } else if (bid < 768) {
        int v = bid - 512;  // b*32 + jt
        int b = v >> 5;
        int jt = v & 31;
        int jb = jt * 64;
#pragma unroll
        for (int k = 0; k < 8; ++k) {
            int idx = t + k * 256;
            int jl = idx >> 5, c4 = idx & 31;
            float4 w = reinterpret_cast<const float4*>(z + ((size_t)(b * NN + jb + jl)) * DD)[c4];
            float* p = &zl[jl * 129 + c4 * 4];
            p[0] = w.x; p[1] = w.y; p[2] = w.z; p[3] = w.w;
        }
        __syncthreads();
#pragma unroll
        for (int k = 0; k < 4; ++k) {
            int sid = t + k * 256;
            int blk = sid >> 6, s = sid & 63;
            int ktl = blk >> 3, nt = blk & 7;
            int d = nt * 16 + (s & 15);
            int jl = ktl * 32 + ((s >> 4) & 3) * 8;
            short8v o;
#pragma unroll
            for (int e = 0; e < 8; ++e) o[e] = f2bf(zl[(jl + e) * 129 + d]);
            *reinterpret_cast<short8v*>(zq + ((size_t)((b * 64 + jt * 2 + ktl) * 8 + nt) * 64 + s) * 8) = o;
        }
    } else {
        int v = bid - 768;
        int q = t & 15;
#pragma unroll
        for (int p = 0; p < 4; ++p) {
            int row = v * 64 + p * 16 + (t >> 4);
            float4 rv = reinterpret_cast<const float4*>(emb + (size_t)row * EE)[q];
            float a0 = __bfloat162float(__float2bfloat16(rv.x));
            float a1 = __bfloat162float(__float2bfloat16(rv.y));
            float a2 = __bfloat162float(__float2bfloat16(rv.z));
            float a3 = __bfloat162float(__float2bfloat16(rv.w));
            float s2 = a0 * a0 + a1 * a1 + a2 * a2 + a3 * a3;
#pragma unroll
            for (int off = 1; off < 16; off <<= 1) s2 += __shfl_xor(s2, off);
            if (q == 0) sq[row] = s2;
        }
    }
}

// ---------------- main MFMA attention: barrier-free streaming ----------------
// grid: bid = ((js*16 + it))*8 + b (XCD-pinned batch). 4 INDEPENDENT waves/block;
// wave owns 32 rows (m=0,1). No __syncthreads anywhere: QK A-fragments + sqj are
// read directly from global (L2-resident: embq 256KB/batch, sq 8KB/batch), PV
// B-operand (zq) likewise. Only LDS use is the wave-private P^T transpose.
// QK (swapped): lane (g,c), group m holds S[i=w*32+m*16+c][j=J*16+4g+r].
// Vote-before-exp per J; whole-tile liveness gates PV (p < 1e-6 truncation,
// bounded out err < ~0.011 worst case for any input).
__global__ __launch_bounds__(256, 2) void attn_mfma(const short* __restrict__ embq,
                                                    const short* __restrict__ zq,
                                                    const float* __restrict__ sq,
                                                    float* __restrict__ outnum,
                                                    float* __restrict__ den,
                                                    int njs) {
    __shared__ short sU[4][2048];  // 16KB: per-wave P^T scratch only (wave-private)

    const int t = threadIdx.x;
    const int bid = blockIdx.x;
    const int b = bid & 7;
    const int q = bid >> 3;
    const int it = q & 15;
    const int js = q >> 4;
    const int ib = it * 128;
    const int w = t >> 6;
    const int l = t & 63;
    const int g = (l >> 4) & 3;
    const int c = l & 15;

    const short8v* embq8 = (const short8v*)embq;
    const short8v* zq8 = (const short8v*)zq;
    const float* sqB = sq + b * NN;

    const int ntiles = 32 / njs;
    const int jt0 = js * ntiles;
    const int jtEnd = jt0 + ntiles;

    // this wave's I fragments (B operand of swapped QK), straight from global
    short8v qkB[2][2];
#pragma unroll
    for (int m = 0; m < 2; ++m)
#pragma unroll
        for (int ke = 0; ke < 2; ++ke)
            qkB[m][ke] = embq8[((size_t)(b * 128 + it * 8 + w * 2 + m) * 2 + ke) * 64 + l];
    float sqi[2];
#pragma unroll
    for (int m = 0; m < 2; ++m) sqi[m] = sqB[ib + w * 32 + m * 16 + c];

    float dsum[2] = {0.f, 0.f};
    float4v acc[2][8];
#pragma unroll
    for (int m = 0; m < 2; ++m)
#pragma unroll
        for (int nt = 0; nt < 8; ++nt) acc[m][nt] = (float4v){0.f, 0.f, 0.f, 0.f};

    char* ptw = (char*)&sU[w][0];
    const int swz = (c & 7) << 4;

    for (int jt = jt0; jt < jtEnd; ++jt) {
        // ---- issue all of this tile's loads up front (L2 hits, ILP) ----
        short8v a[4][2];
        float4 sqj[4];
#pragma unroll
        for (int J = 0; J < 4; ++J) {
            a[J][0] = embq8[((size_t)(b * 128 + jt * 4 + J) * 2 + 0) * 64 + l];
            a[J][1] = embq8[((size_t)(b * 128 + jt * 4 + J) * 2 + 1) * 64 + l];
            sqj[J] = *reinterpret_cast<const float4*>(sqB + jt * 64 + J * 16 + 4 * g);
        }

        bool anyLive = false;
#pragma unroll
        for (int J = 0; J < 4; ++J) {
            float d2[2][4];
            float mn = 1e30f;
#pragma unroll
            for (int m = 0; m < 2; ++m) {
                float4v sfr = (float4v){0.f, 0.f, 0.f, 0.f};
                sfr = __builtin_amdgcn_mfma_f32_16x16x32_bf16(a[J][0], qkB[m][0], sfr, 0, 0, 0);
                sfr = __builtin_amdgcn_mfma_f32_16x16x32_bf16(a[J][1], qkB[m][1], sfr, 0, 0, 0);
                d2[m][0] = fmaxf(fmaf(-2.0f, sfr[0], sqi[m] + sqj[J].x), 0.0f);
                d2[m][1] = fmaxf(fmaf(-2.0f, sfr[1], sqi[m] + sqj[J].y), 0.0f);
                d2[m][2] = fmaxf(fmaf(-2.0f, sfr[2], sqi[m] + sqj[J].z), 0.0f);
                d2[m][3] = fmaxf(fmaf(-2.0f, sfr[3], sqi[m] + sqj[J].w), 0.0f);
                mn = fminf(mn, fminf(fminf(d2[m][0], d2[m][1]), fminf(d2[m][2], d2[m][3])));
            }
            const bool live = !__all(mn > 13.8f);  // wave-uniform
#pragma unroll
            for (int m = 0; m < 2; ++m) {
                unsigned long long pword = 0ull;
                if (live) {
                    float p0 = __expf(-d2[m][0]);
                    float p1 = __expf(-d2[m][1]);
                    float p2 = __expf(-d2[m][2]);
                    float p3 = __expf(-d2[m][3]);
                    dsum[m] += (p0 + p1) + (p2 + p3);
                    pword = (unsigned long long)pack2bf(p0, p1) |
                            ((unsigned long long)pack2bf(p2, p3) << 32);
                }
                // must write even when dead: PV (if tile live) reads every slot
                *reinterpret_cast<unsigned long long*>(
                    ptw + ((m * 2048 + c * 128 + g * 8) ^ swz ^ (J * 32))) = pword;
            }
            anyLive |= live;
        }

        // ---- PV only when some J in this tile carries mass ----
        if (anyLive) {
            short8v pa[2][2];
#pragma unroll
            for (int m = 0; m < 2; ++m)
#pragma unroll
                for (int kt = 0; kt < 2; ++kt)
                    pa[m][kt] = *reinterpret_cast<const short8v*>(
                        ptw + ((m * 2048 + c * 128 + kt * 64 + g * 16) ^ swz));
#pragma unroll
            for (int nt = 0; nt < 8; ++nt) {
                short8v z0 = zq8[(size_t)((b * 64 + jt * 2 + 0) * 8 + nt) * 64 + l];
                short8v z1 = zq8[(size_t)((b * 64 + jt * 2 + 1) * 8 + nt) * 64 + l];
#pragma unroll
                for (int m = 0; m < 2; ++m) {
                    acc[m][nt] = __builtin_amdgcn_mfma_f32_16x16x32_bf16(pa[m][0], z0, acc[m][nt], 0, 0, 0);
                    acc[m][nt] = __builtin_amdgcn_mfma_f32_16x16x32_bf16(pa[m][1], z1, acc[m][nt], 0, 0, 0);
                }
            }
        }
    }

    // dsum reduce over g-groups -> all lanes hold row (m, c) sums
#pragma unroll
    for (int m = 0; m < 2; ++m) {
        dsum[m] += __shfl_xor(dsum[m], 16);
        dsum[m] += __shfl_xor(dsum[m], 32);
    }

    if (njs == 1) {
#pragma unroll
        for (int m = 0; m < 2; ++m) {
            float invr[4];
#pragma unroll
            for (int r = 0; r < 4; ++r) invr[r] = 1.0f / __shfl(dsum[m], 4 * g + r);
#pragma unroll
            for (int r = 0; r < 4; ++r) {
                size_t row = (size_t)(b * NN + ib + w * 32 + m * 16 + 4 * g + r);
#pragma unroll
                for (int nt = 0; nt < 8; ++nt)
                    outnum[row * DD + nt * 16 + c] = acc[m][nt][r] * invr[r];
            }
        }
    } else {
        if (l < 16) {
            den[(size_t)js * BN + b * NN + ib + w * 32 + l] = dsum[0];
            den[(size_t)js * BN + b * NN + ib + w * 32 + 16 + l] = dsum[1];
        }
        // skip num writes when this wave's whole j-slice carries no mass
        if (!__all(fmaxf(dsum[0], dsum[1]) < 1e-6f)) {
#pragma unroll
            for (int m = 0; m < 2; ++m)
#pragma unroll
                for (int r = 0; r < 4; ++r) {
                    size_t row = (size_t)js * BN + b * NN + ib + w * 32 + m * 16 + 4 * g + r;
#pragma unroll
                    for (int nt = 0; nt < 8; ++nt)
                        outnum[row * DD + nt * 16 + c] = acc[m][nt][r];
                }
        }
    }
}

// ---------------- reduce: out = sum_js num / sum_js den, num reads gated by den ----------------
__global__ __launch_bounds__(256) void reduce_kernel(const float4* __restrict__ num,
                                                     const float* __restrict__ den,
                                                     float4* __restrict__ out,
                                                     int njs) {
    int i4 = blockIdx.x * 256 + threadIdx.x;
    int row = i4 >> 5;
    float4 ns = make_float4(0.f, 0.f, 0.f, 0.f);
    float ds = 0.f;
    for (int js = 0; js < njs; ++js) {
        float dj = den[(size_t)js * BN + row];
        ds += dj;
        if (dj >= 1e-6f) {
            float4 v = num[(size_t)js * ((size_t)BN * (DD / 4)) + i4];
            ns.x += v.x; ns.y += v.y; ns.z += v.z; ns.w += v.w;
        }
    }
    float inv = 1.0f / ds;
    out[i4] = make_float4(ns.x * inv, ns.y * inv, ns.z * inv, ns.w * inv);
}

extern "C" void kernel_launch(void* const* d_in, const int* in_sizes, int n_in,
                              void* d_out, int out_size, void* d_ws, size_t ws_size,
                              hipStream_t stream) {
    (void)in_sizes; (void)n_in; (void)out_size;
    const float* emb = (const float*)d_in[0];
    const float* z = (const float*)d_in[1];
    float* out = (float*)d_out;
    float* ws = (float*)d_ws;

    // ws layout (floats): sq[BN] | den[njs*BN] | num[njs*BN*DD] | embq(1M shorts) | zq(2M shorts)
    int njs = 1;
    if (ws_size >= 40ull * 1024 * 1024) njs = 4;
    else if (ws_size >= 24ull * 1024 * 1024) njs = 2;

    float* sqw = ws;
    float* denw = ws + BN;
    float* numw = denw + (size_t)njs * BN;
    size_t numFloats = (njs > 1) ? (size_t)njs * BN * DD : 0;
    short* embqw = (short*)(numw + numFloats);
    short* zqw = embqw + (size_t)BB * NN * EE;

    prep_kernel<<<1024, 256, 0, stream>>>(emb, z, embqw, zqw, sqw);

    attn_mfma<<<8 * 16 * njs, 256, 0, stream>>>(embqw, zqw, sqw,
                                                njs == 1 ? out : numw, denw, njs);

    if (njs > 1) {
        reduce_kernel<<<(BN * (DD / 4)) / 256, 256, 0, stream>>>(
            (const float4*)numw, denw, (float4*)out, njs);
    }
}